// Round 9
// baseline (107.992 us; speedup 1.0000x reference)
//
#include <hip/hip_runtime.h>

// Problem constants (match reference)
constexpr int B = 16;
constexpr int N = 100000;
constexpr int E = 10;
constexpr int D = 3;

typedef float        f32x4 __attribute__((ext_vector_type(4)));
typedef unsigned int u32x4 __attribute__((ext_vector_type(4)));

__device__ __forceinline__ unsigned int bf16_rne(float f) {
    unsigned int u = __float_as_uint(f);
    u += 0x7fffu + ((u >> 16) & 1u);   // round-to-nearest-even
    return u >> 16;
}
__device__ __forceinline__ float bf16_lo(unsigned long long w) {
    return __uint_as_float((unsigned int)w << 16);
}
__device__ __forceinline__ float bf16_hi(unsigned long long w) {
    return __uint_as_float((unsigned int)w & 0xffff0000u);
}
__device__ __forceinline__ float bf16_w2(unsigned long long w) {
    return __uint_as_float((unsigned int)(w >> 32) << 16);
}

// ---------------------------------------------------------------------------
// diff kernel: diff = coord2 - coord1 packed as bf16 {x,y,z,pad} 8B/node.
// Also zeroes the output accumulator (replaces the memset dispatch).
// ---------------------------------------------------------------------------
__global__ __launch_bounds__(256) void diff_bf16_kernel(const float* __restrict__ c1,
                                                        const float* __restrict__ c2,
                                                        unsigned int* __restrict__ outp,
                                                        float* __restrict__ out,
                                                        int nquad) {  // B*N/4
    if (blockIdx.x == 0 && threadIdx.x == 0) *out = 0.0f;
    int per = gridDim.x >> 3;
    int w = (blockIdx.x & 7) * per + (blockIdx.x >> 3);
    int i = w * blockDim.x + threadIdx.x;
    if (i >= nquad) return;
    const f32x4* a4 = reinterpret_cast<const f32x4*>(c1) + (size_t)i * 3;
    const f32x4* b4 = reinterpret_cast<const f32x4*>(c2) + (size_t)i * 3;
    f32x4 a0 = __builtin_nontemporal_load(a4 + 0);
    f32x4 a1 = __builtin_nontemporal_load(a4 + 1);
    f32x4 a2 = __builtin_nontemporal_load(a4 + 2);
    f32x4 b0 = __builtin_nontemporal_load(b4 + 0);
    f32x4 b1 = __builtin_nontemporal_load(b4 + 1);
    f32x4 b2 = __builtin_nontemporal_load(b4 + 2);
    float d[12];
    d[0] = b0.x - a0.x; d[1] = b0.y - a0.y; d[2]  = b0.z - a0.z; d[3]  = b0.w - a0.w;
    d[4] = b1.x - a1.x; d[5] = b1.y - a1.y; d[6]  = b1.z - a1.z; d[7]  = b1.w - a1.w;
    d[8] = b2.x - a2.x; d[9] = b2.y - a2.y; d[10] = b2.z - a2.z; d[11] = b2.w - a2.w;

    u32x4 o0, o1;
    o0.x = bf16_rne(d[0]) | (bf16_rne(d[1]) << 16);   // node 4i
    o0.y = bf16_rne(d[2]);
    o0.z = bf16_rne(d[3]) | (bf16_rne(d[4]) << 16);   // node 4i+1
    o0.w = bf16_rne(d[5]);
    o1.x = bf16_rne(d[6]) | (bf16_rne(d[7]) << 16);   // node 4i+2
    o1.y = bf16_rne(d[8]);
    o1.z = bf16_rne(d[9]) | (bf16_rne(d[10]) << 16);  // node 4i+3
    o1.w = bf16_rne(d[11]);

    u32x4* o = reinterpret_cast<u32x4*>(outp) + (size_t)i * 2;
    o[0] = o0;
    o[1] = o1;
}

// ---------------------------------------------------------------------------
// loss kernel: per-node laplacian-of-diff squared -> block reduce -> atomicAdd
// Gathers: 10 buffer_load_dwordx2 through an SRD with num_records = slab
// bytes. Invalid neighbors get voffset 0xFFFFFF00 -> hardware bounds check
// drops the lane in the TA (no cache request) and returns 0 -- masked
// gather semantics with zero exec-mask overhead and full MLP. ~22% of
// gather lanes are invalid, so if the per-lane address-processing wall is
// real this cuts straight into it.
// ---------------------------------------------------------------------------
__global__ __launch_bounds__(256, 8) void loss_kernel(const unsigned int* __restrict__ diff,
                                                      const int* __restrict__ A,
                                                      float* __restrict__ out) {
    int per = gridDim.x >> 3;
    int w = (blockIdx.x & 7) * per + (blockIdx.x >> 3);
    int node = w * blockDim.x + threadIdx.x;

    float sq = 0.0f;
    if (node < B * N) {
        int b = node / N;  // magic-mul
        // A row: 10 ints, 40B, 8B-aligned; nt (stream-once)
        const long long* ap = reinterpret_cast<const long long*>(A + (size_t)node * E);
        long long q0 = __builtin_nontemporal_load(ap + 0);
        long long q1 = __builtin_nontemporal_load(ap + 1);
        long long q2 = __builtin_nontemporal_load(ap + 2);
        long long q3 = __builtin_nontemporal_load(ap + 3);
        long long q4 = __builtin_nontemporal_load(ap + 4);
        int idx[E] = {(int)q0, (int)(q0 >> 32), (int)q1, (int)(q1 >> 32),
                      (int)q2, (int)(q2 >> 32), (int)q3, (int)(q3 >> 32),
                      (int)q4, (int)(q4 >> 32)};

        // SRD over the whole diff slab (16 batches x N x 8B = 12.8e6 bytes).
        unsigned long long base = (unsigned long long)diff;
        u32x4 srd;
        srd.x = (unsigned int)base;
        srd.y = (unsigned int)(base >> 32);       // stride=0 -> raw bytes
        srd.z = (unsigned int)(B * N * 8);        // num_records = 12,800,000
        srd.w = 0x00020000u;                      // raw untyped dword SRD

        unsigned int bn8 = (unsigned int)(b * N) * 8u;
        unsigned int vo[E];
        float fcnt = 0.f;
        #pragma unroll
        for (int e = 0; e < E; ++e) {
            int ix = idx[e];
            vo[e] = (ix >= 0) ? bn8 + (unsigned int)ix * 8u : 0xFFFFFF00u;
            fcnt += (ix >= 0) ? 1.0f : 0.0f;
        }

        unsigned long long g0, g1, g2, g3, g4, g5, g6, g7, g8, g9;
        asm volatile(
            "buffer_load_dwordx2 %0, %10, %20, 0 offen\n\t"
            "buffer_load_dwordx2 %1, %11, %20, 0 offen\n\t"
            "buffer_load_dwordx2 %2, %12, %20, 0 offen\n\t"
            "buffer_load_dwordx2 %3, %13, %20, 0 offen\n\t"
            "buffer_load_dwordx2 %4, %14, %20, 0 offen\n\t"
            "buffer_load_dwordx2 %5, %15, %20, 0 offen\n\t"
            "buffer_load_dwordx2 %6, %16, %20, 0 offen\n\t"
            "buffer_load_dwordx2 %7, %17, %20, 0 offen\n\t"
            "buffer_load_dwordx2 %8, %18, %20, 0 offen\n\t"
            "buffer_load_dwordx2 %9, %19, %20, 0 offen\n\t"
            "s_waitcnt vmcnt(0)"
            : "=&v"(g0), "=&v"(g1), "=&v"(g2), "=&v"(g3), "=&v"(g4),
              "=&v"(g5), "=&v"(g6), "=&v"(g7), "=&v"(g8), "=&v"(g9)
            : "v"(vo[0]), "v"(vo[1]), "v"(vo[2]), "v"(vo[3]), "v"(vo[4]),
              "v"(vo[5]), "v"(vo[6]), "v"(vo[7]), "v"(vo[8]), "v"(vo[9]),
              "s"(srd)
            : "memory");

        const unsigned long long* db =
            reinterpret_cast<const unsigned long long*>(diff) + (size_t)b * N;
        unsigned long long ov = db[node - b * N];   // coalesced own read

        // invalid lanes returned 0 -> sum directly, no masks needed
        unsigned long long gv[E] = {g0, g1, g2, g3, g4, g5, g6, g7, g8, g9};
        float sx = 0.f, sy = 0.f, sz = 0.f;
        #pragma unroll
        for (int e = 0; e < E; ++e) {
            sx += bf16_lo(gv[e]);
            sy += bf16_hi(gv[e]);
            sz += bf16_w2(gv[e]);
        }
        float inv = 1.0f / fcnt;           // fcnt >= 1 (slot 0 valid)
        float lx = bf16_lo(ov) - sx * inv;
        float ly = bf16_hi(ov) - sy * inv;
        float lz = bf16_w2(ov) - sz * inv;
        sq = lx * lx + ly * ly + lz * lz;
    }

    #pragma unroll
    for (int off = 32; off > 0; off >>= 1)
        sq += __shfl_down(sq, off, 64);

    __shared__ float wsum[4];
    int lane = threadIdx.x & 63;
    int wid = threadIdx.x >> 6;
    if (lane == 0) wsum[wid] = sq;
    __syncthreads();
    if (threadIdx.x == 0) {
        float t = (wsum[0] + wsum[1]) + (wsum[2] + wsum[3]);
        // loss = sum/(B*N*D) * N = sum/(B*D)
        atomicAdd(out, t * (1.0f / (float)(B * D)));
    }
}

extern "C" void kernel_launch(void* const* d_in, const int* in_sizes, int n_in,
                              void* d_out, int out_size, void* d_ws, size_t ws_size,
                              hipStream_t stream) {
    const float* coord1 = (const float*)d_in[0];
    const float* coord2 = (const float*)d_in[1];
    const int* A_list = (const int*)d_in[2];
    float* out = (float*)d_out;
    unsigned int* diff = (unsigned int*)d_ws;   // B*N*8 bytes = 12.8 MB

    int nodes = B * N;       // 1.6M
    int nquad = nodes / 4;   // 400000
    int dblk = (nquad + 255) / 256;  // 1563
    dblk = (dblk + 7) & ~7;          // 1568, multiple of 8 for swizzle
    diff_bf16_kernel<<<dblk, 256, 0, stream>>>(coord1, coord2, diff, out, nquad);

    int nblk = (nodes + 255) / 256;  // 6250
    nblk = (nblk + 7) & ~7;          // 6256
    loss_kernel<<<nblk, 256, 0, stream>>>(diff, A_list, out);
}